// Round 1
// 185.278 us; speedup vs baseline: 1.0337x; 1.0337x over previous
//
#include <hip/hip_runtime.h>
#include <hip/hip_bf16.h>

// ---------------------------------------------------------------------------
// GraphSAGE 2-layer: h = relu(mean_agg(x) @ W1l^T + b1 + x @ W1r^T)
//                    out = mean_agg(h) @ W2l^T + b2 + h @ W2r^T
// N=50000, E=800000, C: 128 -> 256 -> 2.
// Round 16 (this session R0): tail cleanup on top of round-12 structure.
//  - xh buffer eliminated: gather reads the right half of Abf directly
//    (identical bytes; saves a 12.8 MB store in scatter_conv).
//  - combine2 + pr_part eliminated: gemm1 epilogue atomicAdd's reduced
//    partials straight into p2/rs (4 contributions per output float).
//    p2/rs zeroed by widening the existing bcnt memset (contiguous layout).
//  - fin_bucket rewritten atomic-free: sort_gather persists the dst-sorted
//    src list (ushort, in-place over binned) + per-node boffs; fin_bucket
//    walks contiguous segments, 2 threads per node, no LDS atomics.
// Pipeline (5 dispatches): memset(bcnt|p2|rs) -> scatter_conv -> sort_gather
// -> gemm1_fused -> fin_bucket.
// Prior failed experiments (kept for the record):
//  - R13: full-width 1024-thr GEMM w/ in-block projection reduce -> 62 KB LDS
//    caps 2 blk/CU, +56% bank conflicts, GEMM 51 us. Regressed.
//  - R14: last-block-combines w/ __threadfence -> device-scope L2 writeback
//    per block (782x), GEMM 157 us. Regressed hard.
// ---------------------------------------------------------------------------

#define IN_C 128
#define HID_C 256
#define BKT_SHIFT 7
#define BKT_W 128            // dsts per bucket
#define CAP 3072             // bucket slot capacity (mean 2048, sigma 45)

typedef __attribute__((ext_vector_type(8))) short short8;   // 8 bf16 (4 VGPRs)
typedef __attribute__((ext_vector_type(4))) float f32x4;    // MFMA accumulator

static __device__ __forceinline__ unsigned short f2b(float f) {
    __hip_bfloat16 h = __float2bfloat16(f);
    return *(unsigned short*)&h;
}
static __device__ __forceinline__ float b2f(unsigned short u) {
    unsigned v = ((unsigned)u) << 16;
    return *(float*)&v;
}

// ---- fused conversions + direct bucket scatter -----------------------------
// Blocks [0, xblk): fill right half of A with bf16(x). (512 thr)
// Blocks [xblk, xblk+128): Bg = bf16([W1l | W1r]).
// Blocks [xblk+128, ...): scatter 2048 edges/block into fixed bucket slots.
__global__ __launch_bounds__(512) void scatter_conv(
    const float* __restrict__ x, unsigned int* __restrict__ Abf,
    const float* __restrict__ w1l, const float* __restrict__ w1r,
    unsigned short* __restrict__ Bg,
    const int* __restrict__ ei, int* __restrict__ bcnt,
    unsigned int* __restrict__ binned,
    int npairs /* N*64 */, int xblk, int E_) {
    __shared__ int hist[512];
    __shared__ int lbase[512];
    const int tid = threadIdx.x;
    if (blockIdx.x < xblk) {
        int t = blockIdx.x * 512 + tid;
        if (t >= npairs) return;
        float2 v = *(const float2*)&x[(size_t)t * 2];
        unsigned int o = ((unsigned)f2b(v.y) << 16) | f2b(v.x);
        int node = t >> 6, g = t & 63;
        Abf[(size_t)node * 128 + 64 + g] = o;   // A row = 256 bf16 = 128 uints
    } else if (blockIdx.x < xblk + 128) {
        int idx = (blockIdx.x - xblk) * 512 + tid;   // 65536
        int o = idx >> 8, k = idx & 255;
        float f = (k < IN_C) ? w1l[o * IN_C + k] : w1r[o * IN_C + (k - IN_C)];
        Bg[idx] = f2b(f);
    } else {
        const int e0 = (blockIdx.x - xblk - 128) * 2048;
        hist[tid] = 0;
        __syncthreads();
        int dreg[4];
#pragma unroll
        for (int j = 0; j < 4; ++j) {
            int e = e0 + j * 512 + tid;
            dreg[j] = (e < E_) ? ei[E_ + e] : -1;
            if (dreg[j] >= 0) atomicAdd(&hist[dreg[j] >> BKT_SHIFT], 1);
        }
        __syncthreads();
        {
            int c = hist[tid];
            lbase[tid] = c ? tid * CAP + atomicAdd(&bcnt[tid], c) : 0;
            hist[tid] = 0;   // reuse as local cursor
        }
        __syncthreads();
#pragma unroll
        for (int j = 0; j < 4; ++j) {
            int e = e0 + j * 512 + tid;
            if (dreg[j] >= 0) {
                int d = dreg[j];
                int b = d >> BKT_SHIFT;
                int pos = lbase[b] + atomicAdd(&hist[b], 1);
                if (pos < b * CAP + CAP)   // +22 sigma guard, never taken
                    binned[pos] = ((unsigned)ei[e] << BKT_SHIFT) |
                                  (unsigned)(d & (BKT_W - 1));
            }
        }
    }
}

// ---- per-bucket LDS sort + immediate neighbor gather -----------------------
// Also persists the sorted src list (ushort, in-place over binned) and the
// per-node segment offsets for the atomic-free fin_bucket.

__global__ __launch_bounds__(1024) void sort_gather(
    unsigned int* __restrict__ binned, const int* __restrict__ bcnt,
    const uint4* __restrict__ abf4c, uint4* __restrict__ Abf4,
    int* __restrict__ deg, int* __restrict__ boffs, int n) {
    __shared__ unsigned int ebuf[CAP];        // 12 KB
    __shared__ unsigned short sbuf[CAP];      // 6 KB
    __shared__ int hist[BKT_W];
    __shared__ int offs[BKT_W];
    __shared__ int cur[BKT_W];
    const int tid = threadIdx.x;
    const int lane = tid & 63;
    const int bkt = blockIdx.x;
    const int gbase = bkt * CAP;
    int cnt = bcnt[bkt];
    if (cnt > CAP) cnt = CAP;

    if (tid < BKT_W) hist[tid] = 0;
    for (int i = tid; i < cnt; i += 1024) ebuf[i] = binned[gbase + i];
    __syncthreads();
    for (int i = tid; i < cnt; i += 1024)
        atomicAdd(&hist[ebuf[i] & (BKT_W - 1)], 1);
    __syncthreads();
    if (tid < 64) {   // single-wave scan of 128 counts, 2/lane
        int h0 = hist[lane * 2], h1 = hist[lane * 2 + 1];
        int s = h0 + h1;
        int incl = s;
#pragma unroll
        for (int off = 1; off < 64; off <<= 1) {
            int t = __shfl_up(incl, off);
            if (lane >= off) incl += t;
        }
        int excl = incl - s;
        offs[lane * 2] = excl;          cur[lane * 2] = excl;
        offs[lane * 2 + 1] = excl + h0; cur[lane * 2 + 1] = excl + h0;
    }
    __syncthreads();
    for (int i = tid; i < cnt; i += 1024) {
        unsigned int pk = ebuf[i];
        int pos = atomicAdd(&cur[pk & (BKT_W - 1)], 1);
        sbuf[pos] = (unsigned short)(pk >> BKT_SHIFT);   // src (< 65536)
    }
    if (tid < BKT_W) {
        int node = bkt * BKT_W + tid;
        if (node < n) { deg[node] = hist[tid]; boffs[node] = offs[tid]; }
    }
    __syncthreads();

    // persist sorted src list over our own (fully consumed) binned region;
    // overlaps with the gather phase below.
    {
        unsigned short* sout = (unsigned short*)(binned + gbase);
        for (int i = tid; i < cnt; i += 1024) sout[i] = sbuf[i];
    }

    // gather phase: wave wv handles local dsts [wv*8, wv*8+8)
    const int wv = tid >> 6;
    const int ep = lane >> 4;
    const int pos = lane & 15;
    for (int ld = wv * 8; ld < wv * 8 + 8; ++ld) {
        int node = bkt * BKT_W + ld;
        if (node >= n) break;
        int beg = offs[ld], end = offs[ld] + hist[ld];
        float s[8] = {0.f, 0.f, 0.f, 0.f, 0.f, 0.f, 0.f, 0.f};
        for (int e = beg; e < end; e += 8) {
#pragma unroll
            for (int g = 0; g < 2; ++g) {
                int eg = e + g * 4 + ep;
                if (eg < end) {
                    int src = sbuf[eg];
                    // right half of Abf row (== bf16(x) for this src)
                    uint4 u = abf4c[(size_t)src * 32 + 16 + pos];
                    s[0] += b2f(u.x & 0xffff); s[1] += b2f(u.x >> 16);
                    s[2] += b2f(u.y & 0xffff); s[3] += b2f(u.y >> 16);
                    s[4] += b2f(u.z & 0xffff); s[5] += b2f(u.z >> 16);
                    s[6] += b2f(u.w & 0xffff); s[7] += b2f(u.w >> 16);
                }
            }
        }
#pragma unroll
        for (int i = 0; i < 8; ++i) {
            s[i] += __shfl_xor(s[i], 16);
            s[i] += __shfl_xor(s[i], 32);
        }
        if (ep == 0) {
            float inv = 1.0f / (float)max(end - beg, 1);
            uint4 o;
            o.x = ((unsigned)f2b(s[1] * inv) << 16) | f2b(s[0] * inv);
            o.y = ((unsigned)f2b(s[3] * inv) << 16) | f2b(s[2] * inv);
            o.z = ((unsigned)f2b(s[5] * inv) << 16) | f2b(s[4] * inv);
            o.w = ((unsigned)f2b(s[7] * inv) << 16) | f2b(s[6] * inv);
            Abf4[(size_t)node * 32 + pos] = o;   // left half of A row
        }
    }
}

// ---- Layer-1 GEMM + fused layer-2 projection -------------------------------
// 256 thr, 128 rows x 128 cols, grid (391, 2). Reduced projection partials
// go straight to p2/rs via global f32 atomicAdd (4 contributions/output).

#define LSTR 72

__global__ __launch_bounds__(256) void gemm1_fused(
    const unsigned short* __restrict__ Abf, const unsigned short* __restrict__ Bg,
    const float* __restrict__ b1, const float* __restrict__ w2l,
    const float* __restrict__ w2r, float* __restrict__ p2g,
    float* __restrict__ rsg, int nn) {
    __shared__ short As[128 * LSTR];
    __shared__ short Bs[128 * LSTR];

    const int tid = threadIdx.x;
    const int lane = tid & 63;
    const int wid = tid >> 6;
    const int wm = wid >> 1, wn = wid & 1;
    const int row0 = blockIdx.x * 128;
    const int col0 = blockIdx.y * 128;

    const int srow = tid >> 1;
    const int skc = (tid & 1) * 32;
    int arow = row0 + srow;
    if (arow >= nn) arow = nn - 1;
    const size_t agoff = (size_t)arow * 256 + skc;
    const size_t bgoff = (size_t)(col0 + srow) * 256 + skc;

    f32x4 acc[4][4];
#pragma unroll
    for (int i = 0; i < 4; ++i)
#pragma unroll
        for (int j = 0; j < 4; ++j) acc[i][j] = (f32x4){0.f, 0.f, 0.f, 0.f};

    const int quad = lane >> 4;     // 0..3
    const int l16 = lane & 15;

    for (int k0 = 0; k0 < 256; k0 += 64) {
        const uint4* ga = (const uint4*)(Abf + agoff + k0);
        const uint4* gb = (const uint4*)(Bg + bgoff + k0);
        uint4 va0 = ga[0], va1 = ga[1], va2 = ga[2], va3 = ga[3];
        uint4 vb0 = gb[0], vb1 = gb[1], vb2 = gb[2], vb3 = gb[3];

        __syncthreads();
        uint4* la = (uint4*)&As[srow * LSTR + skc];
        uint4* lb = (uint4*)&Bs[srow * LSTR + skc];
        la[0] = va0; la[1] = va1; la[2] = va2; la[3] = va3;
        lb[0] = vb0; lb[1] = vb1; lb[2] = vb2; lb[3] = vb3;
        __syncthreads();

#pragma unroll
        for (int kb = 0; kb < 2; ++kb) {
            short8 af[4], bf[4];
#pragma unroll
            for (int mt = 0; mt < 4; ++mt)
                af[mt] = *(const short8*)&As[(wm * 64 + mt * 16 + l16) * LSTR + kb * 32 + quad * 8];
#pragma unroll
            for (int nt = 0; nt < 4; ++nt)
                bf[nt] = *(const short8*)&Bs[(wn * 64 + nt * 16 + l16) * LSTR + kb * 32 + quad * 8];
#pragma unroll
            for (int mt = 0; mt < 4; ++mt)
#pragma unroll
                for (int nt = 0; nt < 4; ++nt)
                    acc[mt][nt] = __builtin_amdgcn_mfma_f32_16x16x32_bf16(
                        af[mt], bf[nt], acc[mt][nt], 0, 0, 0);
        }
    }

    // ---- fused projection epilogue (no h materialization) ----
    // C/D layout: col = l16, row = quad*4 + reg (m89-verified).
    const int cbase = col0 + wn * 64 + l16;
#pragma unroll
    for (int half = 0; half < 2; ++half) {
        const float* wA = half ? w2r : w2l;          // rows 0,1 of W2{l,r}
        float* og = half ? rsg : p2g;
        f32x4 part[2][4];
#pragma unroll
        for (int c = 0; c < 2; ++c)
#pragma unroll
            for (int mt = 0; mt < 4; ++mt) part[c][mt] = (f32x4){0.f, 0.f, 0.f, 0.f};
#pragma unroll
        for (int nt = 0; nt < 4; ++nt) {
            const int col = cbase + nt * 16;
            const float bias = b1[col];
            const float w0 = wA[col];
            const float w1 = wA[HID_C + col];
#pragma unroll
            for (int mt = 0; mt < 4; ++mt)
#pragma unroll
                for (int r = 0; r < 4; ++r) {
                    float hv = fmaxf(acc[mt][nt][r] + bias, 0.0f);
                    part[0][mt][r] += hv * w0;
                    part[1][mt][r] += hv * w1;
                }
        }
#pragma unroll
        for (int c = 0; c < 2; ++c)
#pragma unroll
            for (int mt = 0; mt < 4; ++mt)
#pragma unroll
                for (int r = 0; r < 4; ++r)
#pragma unroll
                    for (int m = 1; m < 16; m <<= 1)
                        part[c][mt][r] += __shfl_xor(part[c][mt][r], m);
        if (l16 < 8) {
            const int ch2 = l16 & 1;
            const int mts = l16 >> 1;
#pragma unroll
            for (int r = 0; r < 4; ++r) {
                int row = row0 + wm * 64 + quad * 4 + mts * 16 + r;
                if (row < nn)
                    atomicAdd(&og[row * 2 + ch2], part[ch2][mts][r]);
            }
        }
    }
}

// ---- Layer 2 tail: atomic-free per-segment aggregation + finalize ----------
// 256 thr / bucket; threads (t, t+128) split node t's sorted segment.

__global__ __launch_bounds__(256) void fin_bucket(
    const unsigned int* __restrict__ binned, const int* __restrict__ boffs,
    const int* __restrict__ deg,
    const float2* __restrict__ p2, const float2* __restrict__ rs,
    const float* __restrict__ b2, float* __restrict__ out, int n) {
    __shared__ float ps0[BKT_W];
    __shared__ float ps1[BKT_W];
    const int tid = threadIdx.x;
    const int ln = tid & (BKT_W - 1);
    const int hp = tid >> 7;               // 0 or 1
    const int bkt = blockIdx.x;
    const int node = bkt * BKT_W + ln;
    const unsigned short* sp =
        (const unsigned short*)(binned + (size_t)bkt * CAP);
    float s0 = 0.f, s1 = 0.f;
    int dg = 0;
    if (node < n) {
        int beg = boffs[node];
        dg = deg[node];
        int end = beg + dg;
        for (int i = beg + hp; i < end; i += 2) {
            float2 v = p2[sp[i]];
            s0 += v.x; s1 += v.y;
        }
    }
    if (hp) { ps0[ln] = s0; ps1[ln] = s1; }
    __syncthreads();
    if (!hp && node < n) {
        s0 += ps0[ln]; s1 += ps1[ln];
        float inv = 1.0f / (float)max(dg, 1);
        float2 self = rs[node];
        out[node * 2 + 0] = s0 * inv + self.x + b2[0];
        out[node * 2 + 1] = s1 * inv + self.y + b2[1];
    }
}

// ---- launch ----------------------------------------------------------------

extern "C" void kernel_launch(void* const* d_in, const int* in_sizes, int n_in,
                              void* d_out, int out_size, void* d_ws, size_t ws_size,
                              hipStream_t stream) {
    const float* x   = (const float*)d_in[0];
    const int*   ei  = (const int*)d_in[1];
    const float* W1l = (const float*)d_in[2];
    const float* b1  = (const float*)d_in[3];
    const float* W1r = (const float*)d_in[4];
    const float* W2l = (const float*)d_in[5];
    const float* b2  = (const float*)d_in[6];
    const float* W2r = (const float*)d_in[7];
    float* out = (float*)d_out;

    const int N_ = in_sizes[0] / IN_C;      // 50000
    const int E_ = in_sizes[1] / 2;         // 800000
    const int nbkt = (N_ + BKT_W - 1) / BKT_W;   // 391

    char* wsb = (char*)d_ws;
    size_t off = 0;
    auto alloc = [&](size_t bytes) {
        void* ptr = wsb + off;
        off += ((bytes + 15) & ~(size_t)15);
        return ptr;
    };
    unsigned short* Abf = (unsigned short*)alloc((size_t)N_ * 256 * 2);  // 25.6 MB
    unsigned short* Bg  = (unsigned short*)alloc(256 * 256 * 2);         // 128 KB
    unsigned int* binned = (unsigned int*)alloc((size_t)(nbkt + 1) * CAP * 4); // 4.8 MB
    // bcnt, p2, rs contiguous -> single memset clears all three
    int*   bcnt = (int*)alloc(512 * 4);                                  // 2 KB
    float* p2f  = (float*)alloc((size_t)N_ * 2 * 4);                     // 400 KB
    float* rsf  = (float*)alloc((size_t)N_ * 2 * 4);                     // 400 KB
    int*   deg  = (int*)alloc((size_t)N_ * 4);
    int*   boffs = (int*)alloc((size_t)N_ * 4);
    // total ~31.9 MB

    const int xblk = (N_ * 64 + 511) / 512;           // 6250
    const int eblk = (E_ + 2047) / 2048;              // 391

    // dispatch 1: clear bcnt + p2 + rs in one fill (layout is contiguous)
    hipMemsetAsync(bcnt, 0, 512 * sizeof(int) + (size_t)N_ * 2 * 4 * 2, stream);

    // dispatch 2: fused conversions + coarse bucket scatter
    scatter_conv<<<xblk + 128 + eblk, 512, 0, stream>>>(
        x, (unsigned int*)Abf, W1l, W1r, Bg, ei, bcnt, binned,
        N_ * 64, xblk, E_);

    // dispatch 3: per-bucket sort + layer-1 neighbor gather (+ persist sorted)
    sort_gather<<<nbkt, 1024, 0, stream>>>(binned, bcnt, (const uint4*)Abf,
                                           (uint4*)Abf, deg, boffs, N_);

    // dispatch 4: MFMA GEMM with fused layer-2 projection -> atomic p2/rs
    gemm1_fused<<<dim3((N_ + 127) / 128, 2), 256, 0, stream>>>(
        Abf, Bg, b1, W2l, W2r, p2f, rsf, N_);

    // dispatch 5: per-segment aggregate + finalize (no atomics)
    fin_bucket<<<nbkt, 256, 0, stream>>>(binned, boffs, deg,
                                         (const float2*)p2f, (const float2*)rsf,
                                         b2, out, N_);
}

// Round 2
// 179.105 us; speedup vs baseline: 1.0693x; 1.0345x over previous
//
#include <hip/hip_runtime.h>
#include <hip/hip_bf16.h>

// ---------------------------------------------------------------------------
// GraphSAGE 2-layer: h = relu(mean_agg(x) @ W1l^T + b1 + x @ W1r^T)
//                    out = mean_agg(h) @ W2l^T + b2 + h @ W2r^T
// N=50000, E=800000, C: 128 -> 256 -> 2.
// Session R1: attack the two fat kernels.
//  - gemm1_fused: full-width 512-thr blocks (128 rows x 256 cols, 8 waves).
//    A read ONCE (was twice via grid.y=2, -25.6 MB), cross-wave projection
//    partials combined in a 2 KB LDS pr buffer -> p2/rs are plain float2
//    stores (800k global atomics eliminated; p2/rs memset eliminated).
//    LDS 54 KB (< R13's 62 KB blowup), waves/CU preserved (~12).
//  - sort_gather: gather inner loop widened 8->16 edges/iter (4 uint4 loads
//    in flight per lane, was 2) for latency hiding.
//  - fin_bucket: 512 thr, 4 threads/node (was 2).
// Pipeline (5 dispatches): memset(bcnt) -> scatter_conv -> sort_gather
// -> gemm1_fused -> fin_bucket.
// Prior failed experiments (kept for the record):
//  - R13: full-width 1024-thr GEMM w/ in-block projection reduce -> 62 KB LDS
//    caps 2 blk/CU, +56% bank conflicts, GEMM 51 us. Regressed.
//  - R14: last-block-combines w/ __threadfence -> device-scope L2 writeback
//    per block (782x), GEMM 157 us. Regressed hard.
// ---------------------------------------------------------------------------

#define IN_C 128
#define HID_C 256
#define BKT_SHIFT 7
#define BKT_W 128            // dsts per bucket
#define CAP 3072             // bucket slot capacity (mean 2048, sigma 45)

typedef __attribute__((ext_vector_type(8))) short short8;   // 8 bf16 (4 VGPRs)
typedef __attribute__((ext_vector_type(4))) float f32x4;    // MFMA accumulator

static __device__ __forceinline__ unsigned short f2b(float f) {
    __hip_bfloat16 h = __float2bfloat16(f);
    return *(unsigned short*)&h;
}
static __device__ __forceinline__ float b2f(unsigned short u) {
    unsigned v = ((unsigned)u) << 16;
    return *(float*)&v;
}

// ---- fused conversions + direct bucket scatter -----------------------------
// Blocks [0, xblk): fill right half of A with bf16(x). (512 thr)
// Blocks [xblk, xblk+128): Bg = bf16([W1l | W1r]).
// Blocks [xblk+128, ...): scatter 2048 edges/block into fixed bucket slots.
__global__ __launch_bounds__(512) void scatter_conv(
    const float* __restrict__ x, unsigned int* __restrict__ Abf,
    const float* __restrict__ w1l, const float* __restrict__ w1r,
    unsigned short* __restrict__ Bg,
    const int* __restrict__ ei, int* __restrict__ bcnt,
    unsigned int* __restrict__ binned,
    int npairs /* N*64 */, int xblk, int E_) {
    __shared__ int hist[512];
    __shared__ int lbase[512];
    const int tid = threadIdx.x;
    if (blockIdx.x < xblk) {
        int t = blockIdx.x * 512 + tid;
        if (t >= npairs) return;
        float2 v = *(const float2*)&x[(size_t)t * 2];
        unsigned int o = ((unsigned)f2b(v.y) << 16) | f2b(v.x);
        int node = t >> 6, g = t & 63;
        Abf[(size_t)node * 128 + 64 + g] = o;   // A row = 256 bf16 = 128 uints
    } else if (blockIdx.x < xblk + 128) {
        int idx = (blockIdx.x - xblk) * 512 + tid;   // 65536
        int o = idx >> 8, k = idx & 255;
        float f = (k < IN_C) ? w1l[o * IN_C + k] : w1r[o * IN_C + (k - IN_C)];
        Bg[idx] = f2b(f);
    } else {
        const int e0 = (blockIdx.x - xblk - 128) * 2048;
        hist[tid] = 0;
        __syncthreads();
        int dreg[4];
#pragma unroll
        for (int j = 0; j < 4; ++j) {
            int e = e0 + j * 512 + tid;
            dreg[j] = (e < E_) ? ei[E_ + e] : -1;
            if (dreg[j] >= 0) atomicAdd(&hist[dreg[j] >> BKT_SHIFT], 1);
        }
        __syncthreads();
        {
            int c = hist[tid];
            lbase[tid] = c ? tid * CAP + atomicAdd(&bcnt[tid], c) : 0;
            hist[tid] = 0;   // reuse as local cursor
        }
        __syncthreads();
#pragma unroll
        for (int j = 0; j < 4; ++j) {
            int e = e0 + j * 512 + tid;
            if (dreg[j] >= 0) {
                int d = dreg[j];
                int b = d >> BKT_SHIFT;
                int pos = lbase[b] + atomicAdd(&hist[b], 1);
                if (pos < b * CAP + CAP)   // +22 sigma guard, never taken
                    binned[pos] = ((unsigned)ei[e] << BKT_SHIFT) |
                                  (unsigned)(d & (BKT_W - 1));
            }
        }
    }
}

// ---- per-bucket LDS sort + immediate neighbor gather -----------------------
// Also persists the sorted src list (ushort, in-place over binned) and the
// per-node segment offsets for the atomic-free fin_bucket.

__global__ __launch_bounds__(1024) void sort_gather(
    unsigned int* __restrict__ binned, const int* __restrict__ bcnt,
    const uint4* __restrict__ abf4c, uint4* __restrict__ Abf4,
    int* __restrict__ deg, int* __restrict__ boffs, int n) {
    __shared__ unsigned int ebuf[CAP];        // 12 KB
    __shared__ unsigned short sbuf[CAP];      // 6 KB
    __shared__ int hist[BKT_W];
    __shared__ int offs[BKT_W];
    __shared__ int cur[BKT_W];
    const int tid = threadIdx.x;
    const int lane = tid & 63;
    const int bkt = blockIdx.x;
    const int gbase = bkt * CAP;
    int cnt = bcnt[bkt];
    if (cnt > CAP) cnt = CAP;

    if (tid < BKT_W) hist[tid] = 0;
    for (int i = tid; i < cnt; i += 1024) ebuf[i] = binned[gbase + i];
    __syncthreads();
    for (int i = tid; i < cnt; i += 1024)
        atomicAdd(&hist[ebuf[i] & (BKT_W - 1)], 1);
    __syncthreads();
    if (tid < 64) {   // single-wave scan of 128 counts, 2/lane
        int h0 = hist[lane * 2], h1 = hist[lane * 2 + 1];
        int s = h0 + h1;
        int incl = s;
#pragma unroll
        for (int off = 1; off < 64; off <<= 1) {
            int t = __shfl_up(incl, off);
            if (lane >= off) incl += t;
        }
        int excl = incl - s;
        offs[lane * 2] = excl;          cur[lane * 2] = excl;
        offs[lane * 2 + 1] = excl + h0; cur[lane * 2 + 1] = excl + h0;
    }
    __syncthreads();
    for (int i = tid; i < cnt; i += 1024) {
        unsigned int pk = ebuf[i];
        int pos = atomicAdd(&cur[pk & (BKT_W - 1)], 1);
        sbuf[pos] = (unsigned short)(pk >> BKT_SHIFT);   // src (< 65536)
    }
    if (tid < BKT_W) {
        int node = bkt * BKT_W + tid;
        if (node < n) { deg[node] = hist[tid]; boffs[node] = offs[tid]; }
    }
    __syncthreads();

    // persist sorted src list over our own (fully consumed) binned region;
    // overlaps with the gather phase below.
    {
        unsigned short* sout = (unsigned short*)(binned + gbase);
        for (int i = tid; i < cnt; i += 1024) sout[i] = sbuf[i];
    }

    // gather phase: wave wv handles local dsts [wv*8, wv*8+8)
    const int wv = tid >> 6;
    const int ep = lane >> 4;
    const int pos = lane & 15;
    for (int ld = wv * 8; ld < wv * 8 + 8; ++ld) {
        int node = bkt * BKT_W + ld;
        if (node >= n) break;
        int beg = offs[ld], end = offs[ld] + hist[ld];
        float s[8] = {0.f, 0.f, 0.f, 0.f, 0.f, 0.f, 0.f, 0.f};
        for (int e = beg; e < end; e += 16) {
#pragma unroll
            for (int g = 0; g < 4; ++g) {       // 4 uint4 loads in flight
                int eg = e + g * 4 + ep;
                if (eg < end) {
                    int src = sbuf[eg];
                    // right half of Abf row (== bf16(x) for this src)
                    uint4 u = abf4c[(size_t)src * 32 + 16 + pos];
                    s[0] += b2f(u.x & 0xffff); s[1] += b2f(u.x >> 16);
                    s[2] += b2f(u.y & 0xffff); s[3] += b2f(u.y >> 16);
                    s[4] += b2f(u.z & 0xffff); s[5] += b2f(u.z >> 16);
                    s[6] += b2f(u.w & 0xffff); s[7] += b2f(u.w >> 16);
                }
            }
        }
#pragma unroll
        for (int i = 0; i < 8; ++i) {
            s[i] += __shfl_xor(s[i], 16);
            s[i] += __shfl_xor(s[i], 32);
        }
        if (ep == 0) {
            float inv = 1.0f / (float)max(end - beg, 1);
            uint4 o;
            o.x = ((unsigned)f2b(s[1] * inv) << 16) | f2b(s[0] * inv);
            o.y = ((unsigned)f2b(s[3] * inv) << 16) | f2b(s[2] * inv);
            o.z = ((unsigned)f2b(s[5] * inv) << 16) | f2b(s[4] * inv);
            o.w = ((unsigned)f2b(s[7] * inv) << 16) | f2b(s[6] * inv);
            Abf4[(size_t)node * 32 + pos] = o;   // left half of A row
        }
    }
}

// ---- Layer-1 GEMM + fused layer-2 projection -------------------------------
// 512 thr, full-width tile: 128 rows x 256 cols, 8 waves (2 row x 4 col).
// A read once per block. Projection partials shuffle-reduced per wave, then
// combined across waves in LDS pr[128][4]; p2/rs written with plain stores.

#define LSTR 72

__global__ __launch_bounds__(512) void gemm1_fused(
    const unsigned short* __restrict__ Abf, const unsigned short* __restrict__ Bg,
    const float* __restrict__ b1, const float* __restrict__ w2l,
    const float* __restrict__ w2r, float2* __restrict__ p2g,
    float2* __restrict__ rsg, int nn) {
    __shared__ short As[128 * LSTR];          // 18.4 KB
    __shared__ short Bs[256 * LSTR];          // 36.9 KB

    const int tid = threadIdx.x;
    const int lane = tid & 63;
    const int wid = tid >> 6;                 // 0..7
    const int wm = wid >> 2, wn = wid & 3;    // 2 x 4 wave grid
    const int row0 = blockIdx.x * 128;

    // A staging: 128 rows, 4 segs of 16 shorts (2 uint4 per thread)
    const int a_row = tid >> 2, a_seg = tid & 3;
    int arow = row0 + a_row;
    if (arow >= nn) arow = nn - 1;
    const size_t agoff = (size_t)arow * 256 + a_seg * 16;
    // B staging: 256 rows, 2 segs of 32 shorts (4 uint4 per thread)
    const int b_row = tid >> 1, b_seg = tid & 1;
    const size_t bgoff = (size_t)b_row * 256 + b_seg * 32;

    f32x4 acc[4][4];
#pragma unroll
    for (int i = 0; i < 4; ++i)
#pragma unroll
        for (int j = 0; j < 4; ++j) acc[i][j] = (f32x4){0.f, 0.f, 0.f, 0.f};

    const int quad = lane >> 4;     // 0..3
    const int l16 = lane & 15;

    for (int k0 = 0; k0 < 256; k0 += 64) {
        const uint4* ga = (const uint4*)(Abf + agoff + k0);
        const uint4* gb = (const uint4*)(Bg + bgoff + k0);
        uint4 va0 = ga[0], va1 = ga[1];
        uint4 vb0 = gb[0], vb1 = gb[1], vb2 = gb[2], vb3 = gb[3];

        __syncthreads();
        uint4* la = (uint4*)&As[a_row * LSTR + a_seg * 16];
        la[0] = va0; la[1] = va1;
        uint4* lb = (uint4*)&Bs[b_row * LSTR + b_seg * 32];
        lb[0] = vb0; lb[1] = vb1; lb[2] = vb2; lb[3] = vb3;
        __syncthreads();

#pragma unroll
        for (int kb = 0; kb < 2; ++kb) {
            short8 af[4], bf[4];
#pragma unroll
            for (int mt = 0; mt < 4; ++mt)
                af[mt] = *(const short8*)&As[(wm * 64 + mt * 16 + l16) * LSTR + kb * 32 + quad * 8];
#pragma unroll
            for (int nt = 0; nt < 4; ++nt)
                bf[nt] = *(const short8*)&Bs[(wn * 64 + nt * 16 + l16) * LSTR + kb * 32 + quad * 8];
#pragma unroll
            for (int mt = 0; mt < 4; ++mt)
#pragma unroll
                for (int nt = 0; nt < 4; ++nt)
                    acc[mt][nt] = __builtin_amdgcn_mfma_f32_16x16x32_bf16(
                        af[mt], bf[nt], acc[mt][nt], 0, 0, 0);
        }
    }

    // ---- fused projection epilogue (no h materialization) ----
    // C/D layout: col = l16, row = quad*4 + reg (m89-verified).
    // Per-wave 16-lane shuffle reduce, then cross-wave combine in LDS pr.
    float* pr = (float*)As;                    // 128 rows x 4 outs = 2 KB
    __syncthreads();                           // all ds_reads of As done
    pr[tid % 512] = 0.f;                       // tid<512 covers 512 floats
    __syncthreads();

    const int cbase = wn * 64 + l16;
#pragma unroll
    for (int half = 0; half < 2; ++half) {
        const float* wA = half ? w2r : w2l;          // rows 0,1 of W2{l,r}
        f32x4 part[2][4];
#pragma unroll
        for (int c = 0; c < 2; ++c)
#pragma unroll
            for (int mt = 0; mt < 4; ++mt) part[c][mt] = (f32x4){0.f, 0.f, 0.f, 0.f};
#pragma unroll
        for (int nt = 0; nt < 4; ++nt) {
            const int col = cbase + nt * 16;
            const float bias = b1[col];
            const float w0 = wA[col];
            const float w1 = wA[HID_C + col];
#pragma unroll
            for (int mt = 0; mt < 4; ++mt)
#pragma unroll
                for (int r = 0; r < 4; ++r) {
                    float hv = fmaxf(acc[mt][nt][r] + bias, 0.0f);
                    part[0][mt][r] += hv * w0;
                    part[1][mt][r] += hv * w1;
                }
        }
#pragma unroll
        for (int c = 0; c < 2; ++c)
#pragma unroll
            for (int mt = 0; mt < 4; ++mt)
#pragma unroll
                for (int r = 0; r < 4; ++r)
#pragma unroll
                    for (int m = 1; m < 16; m <<= 1)
                        part[c][mt][r] += __shfl_xor(part[c][mt][r], m);
        if (l16 < 8) {
            const int ch2 = l16 & 1;
            const int mts = l16 >> 1;
#pragma unroll
            for (int r = 0; r < 4; ++r) {
                int rloc = wm * 64 + quad * 4 + mts * 16 + r;
                atomicAdd(&pr[rloc * 4 + half * 2 + ch2], part[ch2][mts][r]);
            }
        }
    }
    __syncthreads();
    if (tid < 256) {
        int rloc = tid >> 1, pair = tid & 1;
        int row = row0 + rloc;
        if (row < nn) {
            float2 v = make_float2(pr[rloc * 4 + pair * 2],
                                   pr[rloc * 4 + pair * 2 + 1]);
            if (pair) rsg[row] = v; else p2g[row] = v;
        }
    }
}

// ---- Layer 2 tail: atomic-free per-segment aggregation + finalize ----------
// 512 thr / bucket; 4 threads per node split the sorted segment.

__global__ __launch_bounds__(512) void fin_bucket(
    const unsigned int* __restrict__ binned, const int* __restrict__ boffs,
    const int* __restrict__ deg,
    const float2* __restrict__ p2, const float2* __restrict__ rs,
    const float* __restrict__ b2, float* __restrict__ out, int n) {
    __shared__ float ps0[3][BKT_W];
    __shared__ float ps1[3][BKT_W];
    const int tid = threadIdx.x;
    const int ln = tid & (BKT_W - 1);
    const int hp = tid >> 7;               // 0..3
    const int bkt = blockIdx.x;
    const int node = bkt * BKT_W + ln;
    const unsigned short* sp =
        (const unsigned short*)(binned + (size_t)bkt * CAP);
    float s0 = 0.f, s1 = 0.f;
    int dg = 0;
    if (node < n) {
        int beg = boffs[node];
        dg = deg[node];
        int end = beg + dg;
        for (int i = beg + hp; i < end; i += 4) {
            float2 v = p2[sp[i]];
            s0 += v.x; s1 += v.y;
        }
    }
    if (hp) { ps0[hp - 1][ln] = s0; ps1[hp - 1][ln] = s1; }
    __syncthreads();
    if (!hp && node < n) {
        s0 += ps0[0][ln] + ps0[1][ln] + ps0[2][ln];
        s1 += ps1[0][ln] + ps1[1][ln] + ps1[2][ln];
        float inv = 1.0f / (float)max(dg, 1);
        float2 self = rs[node];
        out[node * 2 + 0] = s0 * inv + self.x + b2[0];
        out[node * 2 + 1] = s1 * inv + self.y + b2[1];
    }
}

// ---- launch ----------------------------------------------------------------

extern "C" void kernel_launch(void* const* d_in, const int* in_sizes, int n_in,
                              void* d_out, int out_size, void* d_ws, size_t ws_size,
                              hipStream_t stream) {
    const float* x   = (const float*)d_in[0];
    const int*   ei  = (const int*)d_in[1];
    const float* W1l = (const float*)d_in[2];
    const float* b1  = (const float*)d_in[3];
    const float* W1r = (const float*)d_in[4];
    const float* W2l = (const float*)d_in[5];
    const float* b2  = (const float*)d_in[6];
    const float* W2r = (const float*)d_in[7];
    float* out = (float*)d_out;

    const int N_ = in_sizes[0] / IN_C;      // 50000
    const int E_ = in_sizes[1] / 2;         // 800000
    const int nbkt = (N_ + BKT_W - 1) / BKT_W;   // 391

    char* wsb = (char*)d_ws;
    size_t off = 0;
    auto alloc = [&](size_t bytes) {
        void* ptr = wsb + off;
        off += ((bytes + 15) & ~(size_t)15);
        return ptr;
    };
    unsigned short* Abf = (unsigned short*)alloc((size_t)N_ * 256 * 2);  // 25.6 MB
    unsigned short* Bg  = (unsigned short*)alloc(256 * 256 * 2);         // 128 KB
    unsigned int* binned = (unsigned int*)alloc((size_t)(nbkt + 1) * CAP * 4); // 4.8 MB
    int*   bcnt = (int*)alloc(512 * 4);                                  // 2 KB
    float* p2f  = (float*)alloc((size_t)N_ * 2 * 4);                     // 400 KB
    float* rsf  = (float*)alloc((size_t)N_ * 2 * 4);                     // 400 KB
    int*   deg  = (int*)alloc((size_t)N_ * 4);
    int*   boffs = (int*)alloc((size_t)N_ * 4);
    // total ~31.9 MB

    const int xblk = (N_ * 64 + 511) / 512;           // 6250
    const int eblk = (E_ + 2047) / 2048;              // 391

    // dispatch 1: clear bucket cursors only (p2/rs now plain-stored)
    hipMemsetAsync(bcnt, 0, 512 * sizeof(int), stream);

    // dispatch 2: fused conversions + coarse bucket scatter
    scatter_conv<<<xblk + 128 + eblk, 512, 0, stream>>>(
        x, (unsigned int*)Abf, W1l, W1r, Bg, ei, bcnt, binned,
        N_ * 64, xblk, E_);

    // dispatch 3: per-bucket sort + layer-1 neighbor gather (+ persist sorted)
    sort_gather<<<nbkt, 1024, 0, stream>>>(binned, bcnt, (const uint4*)Abf,
                                           (uint4*)Abf, deg, boffs, N_);

    // dispatch 4: full-width MFMA GEMM with fused layer-2 projection
    gemm1_fused<<<(N_ + 127) / 128, 512, 0, stream>>>(
        Abf, Bg, b1, W2l, W2r, (float2*)p2f, (float2*)rsf, N_);

    // dispatch 5: per-segment aggregate + finalize (no atomics)
    fin_bucket<<<nbkt, 512, 0, stream>>>(binned, boffs, deg,
                                         (const float2*)p2f, (const float2*)rsf,
                                         b2, out, N_);
}